// Round 3
// baseline (1461.722 us; speedup 1.0000x reference)
//
#include <hip/hip_runtime.h>
#include <math.h>

// Problem constants
#define TOK   4096    // B*N
#define EDIM  512
#define HEADS 8
#define DHEAD 64
#define GCOLS 32768   // H*D*D

typedef unsigned short u16;
typedef __attribute__((ext_vector_type(8))) short bf16x8;   // 8 bf16 = 4 VGPRs (MFMA A/B frag)
typedef __attribute__((ext_vector_type(4))) float f32x4;    // MFMA C/D frag
typedef __attribute__((ext_vector_type(4))) unsigned short u16x4;

typedef const __attribute__((address_space(1))) void* gas_ptr;
typedef __attribute__((address_space(3))) void* las_ptr;

__device__ __forceinline__ void gll16(const void* g, void* lds) {
  // async global->LDS, 16B/lane: per-lane global addr, wave-uniform LDS base,
  // lane i lands at lds + i*16
  __builtin_amdgcn_global_load_lds((gas_ptr)g, (las_ptr)lds, 16, 0, 0);
}

__device__ __forceinline__ u16 f2bf(float f) {
  union { float f; unsigned u; } v; v.f = f;
  unsigned r = v.u + 0x7FFFu + ((v.u >> 16) & 1u);   // RNE
  return (u16)(r >> 16);
}
__device__ __forceinline__ float bf2f(u16 h) {
  union { unsigned u; float f; } v; v.u = ((unsigned)h) << 16;
  return v.f;
}
__device__ __forceinline__ float gelu_exact(float x) {
  return 0.5f * x * (1.0f + erff(x * 0.7071067811865475f));
}

// ------------------------------------------------- split x -> bf16 hi + lo pair
__global__ void split_bf16_k(const float* __restrict__ in, u16* __restrict__ oh,
                             u16* __restrict__ ol, int n) {
  int i = (blockIdx.x * blockDim.x + threadIdx.x) * 4;
  if (i + 3 < n) {
    float4 f = *(const float4*)(in + i);
    u16x4 h, l;
    h.x = f2bf(f.x); l.x = f2bf(f.x - bf2f(h.x));
    h.y = f2bf(f.y); l.y = f2bf(f.y - bf2f(h.y));
    h.z = f2bf(f.z); l.z = f2bf(f.z - bf2f(h.z));
    h.w = f2bf(f.w); l.w = f2bf(f.w - bf2f(h.w));
    *(u16x4*)(oh + i) = h;
    *(u16x4*)(ol + i) = l;
  }
}

// -------------------- transpose W[K][N] -> Wt[N][K], split into bf16 hi (+ lo)
__global__ void transpose_split_k(const float* __restrict__ in, u16* __restrict__ oh,
                                  u16* __restrict__ ol, int K, int N) {
  __shared__ float tile[32][33];
  int n0 = blockIdx.x * 32, k0 = blockIdx.y * 32;
  int tx = threadIdx.x, ty = threadIdx.y;  // (32,8)
  #pragma unroll
  for (int i = 0; i < 4; i++)
    tile[ty + i * 8][tx] = in[(size_t)(k0 + ty + i * 8) * N + n0 + tx];
  __syncthreads();
  #pragma unroll
  for (int i = 0; i < 4; i++) {
    float v = tile[tx][ty + i * 8];
    size_t idx = (size_t)(n0 + ty + i * 8) * K + k0 + tx;
    u16 h = f2bf(v);
    oh[idx] = h;
    if (ol) ol[idx] = f2bf(v - bf2f(h));
  }
}

// ---------------------------------------------------------------- QKV GEMM
// 128x128 tile, BK=64, 4 waves (each 64x64). 3 accumulation passes:
//   x_hi@W_hi + x_lo@W_hi + x_hi@W_lo  (residual x_lo@W_lo ~1e-7, dropped)
// q stored fp32 [B][H][N][D]; k stored hi/lo bf16; v stored transposed bf16 [B][H][D][N].
__global__ __launch_bounds__(256, 2) void qkv_gemm_k(
    const u16* __restrict__ xh, const u16* __restrict__ xl,
    const u16* __restrict__ Wqh, const u16* __restrict__ Wql,
    const u16* __restrict__ Wkh, const u16* __restrict__ Wkl,
    const u16* __restrict__ Wvh, const u16* __restrict__ Wvl,
    const float* __restrict__ bq, const float* __restrict__ bk, const float* __restrict__ bv,
    float* __restrict__ qf, u16* __restrict__ kho, u16* __restrict__ klo,
    u16* __restrict__ vTo) {
  __shared__ __align__(16) u16 As[16 * 512];
  __shared__ __align__(16) u16 Bs[16 * 512];
  const int which = blockIdx.z;
  const u16* Whi = which == 0 ? Wqh : (which == 1 ? Wkh : Wvh);
  const u16* Wlo = which == 0 ? Wql : (which == 1 ? Wkl : Wvl);
  const float* bias = which == 0 ? bq : (which == 1 ? bk : bv);
  const int m0 = blockIdx.x * 128;
  const int n0 = blockIdx.y * 128;
  const int tid = threadIdx.x;
  const int w = tid >> 6, lane = tid & 63, l15 = lane & 15, quad = lane >> 4;
  const int mhalf = w >> 1, nhalf = w & 1;

  f32x4 acc[4][4];
  #pragma unroll
  for (int i = 0; i < 4; i++)
    #pragma unroll
    for (int j = 0; j < 4; j++) acc[i][j] = f32x4{0.f, 0.f, 0.f, 0.f};

  for (int pass = 0; pass < 3; pass++) {
    const u16* Ax = (pass == 1) ? xl : xh;
    const u16* Bx = (pass == 2) ? Wlo : Whi;
    for (int kk = 0; kk < 512; kk += 64) {
      #pragma unroll
      for (int i = 0; i < 8; i++) {
        int cb = w * 8 + i;
        if (cb < 16) {
          int ks = cb >> 3, mt = cb & 7;
          gll16(Ax + (size_t)(m0 + mt * 16 + l15) * 512 + kk + ks * 32 + quad * 8,
                As + cb * 512);
        } else {
          int bi = cb - 16, ks = bi >> 3, nt = bi & 7;
          gll16(Bx + (size_t)(n0 + nt * 16 + l15) * 512 + kk + ks * 32 + quad * 8,
                Bs + bi * 512);
        }
      }
      __syncthreads();
      #pragma unroll
      for (int ks = 0; ks < 2; ks++) {
        bf16x8 a[4], b[4];
        #pragma unroll
        for (int mt = 0; mt < 4; mt++)
          a[mt] = *(const bf16x8*)(As + (ks * 8 + mhalf * 4 + mt) * 512 + lane * 8);
        #pragma unroll
        for (int nt = 0; nt < 4; nt++)
          b[nt] = *(const bf16x8*)(Bs + (ks * 8 + nhalf * 4 + nt) * 512 + lane * 8);
        #pragma unroll
        for (int mt = 0; mt < 4; mt++)
          #pragma unroll
          for (int nt = 0; nt < 4; nt++)
            acc[mt][nt] = __builtin_amdgcn_mfma_f32_16x16x32_bf16(a[mt], b[nt], acc[mt][nt], 0, 0, 0);
      }
      __syncthreads();
    }
  }
  #pragma unroll
  for (int nt = 0; nt < 4; nt++) {
    int col = n0 + (nhalf * 4 + nt) * 16 + l15;
    float bia = bias[col];
    int h = col >> 6, d = col & 63;
    #pragma unroll
    for (int mt = 0; mt < 4; mt++) {
      #pragma unroll
      for (int r = 0; r < 4; r++) {
        int t = m0 + (mhalf * 4 + mt) * 16 + quad * 4 + r;
        int b_ = t >> 10, n = t & 1023;
        float val = acc[mt][nt][r] + bia;
        size_t idx = (((size_t)(b_ * 8 + h) * 1024) + n) * 64 + d;
        if (which == 0) {
          qf[idx] = val;
        } else if (which == 1) {
          u16 hh = f2bf(val);
          kho[idx] = hh;
          klo[idx] = f2bf(val - bf2f(hh));
        } else {
          vTo[(((size_t)(b_ * 8 + h) * 64) + d) * 1024 + n] = f2bf(val);
        }
      }
    }
  }
}

// ---------------------------------------------------------------- fused g-GEMM + q.g
// Block = 128 tokens x one head (full 4096-col stripe), 512 threads (8 waves).
// npass accumulation passes per j-chunk: (xh,Wgh), (xl,Wgh), [(xh,Wgl)].
// q kept fp32; qg written as hi/lo bf16 pair.
__global__ __launch_bounds__(512, 2) void qg_fused_k(
    const u16* __restrict__ xh, const u16* __restrict__ xl,
    const u16* __restrict__ Wgh, const u16* __restrict__ Wgl,
    const float* __restrict__ bg, const float* __restrict__ qf,
    u16* __restrict__ qgh, u16* __restrict__ qgl, int npass) {
  __shared__ __align__(16) u16 As[16 * 512];   // 16KB
  __shared__ __align__(16) u16 Bs[16 * 512];   // 16KB
  __shared__ __align__(16) float Qs[128 * 64]; // 32KB fp32 q rows
  const int head = blockIdx.x & 7;             // XCD-pinned per head
  const int t0 = (blockIdx.x >> 3) * 128;
  const int tid = threadIdx.x;
  const int w = tid >> 6, lane = tid & 63, l15 = lane & 15, quad = lane >> 4;
  const int mhalf = w >> 2;   // 0..1  (token half)
  const int ntA = w & 3;      // 0..3  (e-range /16)
  const int b_ = t0 >> 10, nseq0 = t0 & 1023;
  const float* qbase = qf + (((size_t)(b_ * 8 + head) * 1024) + nseq0) * 64;

  // stage Qs (contiguous 32KB fp32). NOTE: global addr must be PER-LANE
  // (base + cb*1024 + lane*16); LDS base wave-uniform.
  #pragma unroll
  for (int i = 0; i < 4; i++) {
    int cb = w * 4 + i;
    gll16((const char*)qbase + (size_t)cb * 1024 + (size_t)lane * 16,
          (char*)Qs + (size_t)cb * 1024);
  }
  f32x4 qg[4];
  #pragma unroll
  for (int i = 0; i < 4; i++) qg[i] = f32x4{0.f, 0.f, 0.f, 0.f};
  __syncthreads();

  for (int j = 0; j < 32; j++) {
    f32x4 zacc[4][2];
    #pragma unroll
    for (int i = 0; i < 4; i++) {
      zacc[i][0] = f32x4{0.f, 0.f, 0.f, 0.f};
      zacc[i][1] = f32x4{0.f, 0.f, 0.f, 0.f};
    }
    const int c0 = head * 4096 + j * 128;
    for (int pass = 0; pass < npass; pass++) {
      const u16* Ax = (pass == 1) ? xl : xh;
      const u16* Bx = (pass == 2) ? Wgl : Wgh;
      for (int kk = 0; kk < 512; kk += 64) {
        #pragma unroll
        for (int i = 0; i < 4; i++) {
          int cb = w * 4 + i;
          if (cb < 16) {
            int ks = cb >> 3, mt = cb & 7;
            gll16(Ax + (size_t)(t0 + mt * 16 + l15) * 512 + kk + ks * 32 + quad * 8,
                  As + cb * 512);
          } else {
            int bi = cb - 16, ks = bi >> 3, nt = bi & 7;
            gll16(Bx + (size_t)(c0 + nt * 16 + l15) * 512 + kk + ks * 32 + quad * 8,
                  Bs + bi * 512);
          }
        }
        __syncthreads();
        #pragma unroll
        for (int ks = 0; ks < 2; ks++) {
          bf16x8 a[4];
          #pragma unroll
          for (int mt = 0; mt < 4; mt++)
            a[mt] = *(const bf16x8*)(As + (ks * 8 + mhalf * 4 + mt) * 512 + lane * 8);
          bf16x8 b0 = *(const bf16x8*)(Bs + (ks * 8 + ntA) * 512 + lane * 8);
          bf16x8 b1 = *(const bf16x8*)(Bs + (ks * 8 + ntA + 4) * 512 + lane * 8);
          #pragma unroll
          for (int mt = 0; mt < 4; mt++) {
            zacc[mt][0] = __builtin_amdgcn_mfma_f32_16x16x32_bf16(a[mt], b0, zacc[mt][0], 0, 0, 0);
            zacc[mt][1] = __builtin_amdgcn_mfma_f32_16x16x32_bf16(a[mt], b1, zacc[mt][1], 0, 0, 0);
          }
        }
        __syncthreads();
      }
    }
    // epilogue: bias + exact gelu + contract with fp32 q over d=2j, 2j+1
    float bg0 = bg[c0 + ntA * 16 + l15];
    float bg1 = bg[c0 + (ntA + 4) * 16 + l15];
    #pragma unroll
    for (int mt = 0; mt < 4; mt++) {
      #pragma unroll
      for (int r = 0; r < 4; r++) {
        int row = mhalf * 64 + mt * 16 + quad * 4 + r;
        float2 qp = *(const float2*)&Qs[row * 64 + 2 * j];
        float g0 = gelu_exact(zacc[mt][0][r] + bg0);
        float g1 = gelu_exact(zacc[mt][1][r] + bg1);
        qg[mt][r] += qp.x * g0 + qp.y * g1;
      }
    }
  }
  const int eb = ntA * 16;
  #pragma unroll
  for (int mt = 0; mt < 4; mt++) {
    #pragma unroll
    for (int r = 0; r < 4; r++) {
      int t = t0 + mhalf * 64 + mt * 16 + quad * 4 + r;
      int bb = t >> 10, n = t & 1023;
      size_t idx = (((size_t)(bb * 8 + head) * 1024) + n) * 64 + eb + l15;
      float val = qg[mt][r];
      u16 hh = f2bf(val);
      qgh[idx] = hh;
      qgl[idx] = f2bf(val - bf2f(hh));
    }
  }
}

// ---------------------------------------------------------------- flash attention
// Block = (b,h,qtile64), 4 waves x 16 q-rows. S = qg@k^T via 3-term hi/lo MFMA
// (hi*kh + lo*kh + hi*kl), online softmax, P->LDS (C->A layout turn), O += P@V.
__global__ __launch_bounds__(256, 2) void attn_k(
    const u16* __restrict__ qgh, const u16* __restrict__ qgl,
    const u16* __restrict__ khb, const u16* __restrict__ klb,
    const u16* __restrict__ vTb, float* __restrict__ out) {
  __shared__ __align__(16) u16 Ksh[8 * 512];
  __shared__ __align__(16) u16 Ksl[8 * 512];
  __shared__ __align__(16) u16 Vs[8 * 512];
  __shared__ __align__(16) u16 Ps[4][16 * 72];    // per-wave P, row stride 72
  const int idx = blockIdx.x;
  const int bh = idx & 31;   // b*8+h -> XCD = bh%8
  const int qt = idx >> 5;
  const int b_ = bh >> 3, h = bh & 7;
  const int tid = threadIdx.x;
  const int w = tid >> 6, lane = tid & 63, l15 = lane & 15, quad = lane >> 4;

  const u16* qghB = qgh + (size_t)bh * 1024 * 64;
  const u16* qglB = qgl + (size_t)bh * 1024 * 64;
  const u16* khB  = khb + (size_t)bh * 1024 * 64;
  const u16* klB  = klb + (size_t)bh * 1024 * 64;
  const u16* vB   = vTb + (size_t)bh * 64 * 1024;

  bf16x8 aqh[2], aql[2];
  #pragma unroll
  for (int ks = 0; ks < 2; ks++) {
    size_t off = (size_t)(qt * 64 + w * 16 + l15) * 64 + ks * 32 + quad * 8;
    aqh[ks] = *(const bf16x8*)(qghB + off);
    aql[ks] = *(const bf16x8*)(qglB + off);
  }

  f32x4 o[4];
  #pragma unroll
  for (int i = 0; i < 4; i++) o[i] = f32x4{0.f, 0.f, 0.f, 0.f};
  float m_old[4], l_old[4];
  #pragma unroll
  for (int r = 0; r < 4; r++) { m_old[r] = -1e30f; l_old[r] = 0.f; }

  for (int kt = 0; kt < 16; kt++) {
    #pragma unroll
    for (int i = 0; i < 2; i++) {
      int cb = w * 2 + i;
      int ks = cb >> 2, nt = cb & 3;
      size_t koff = (size_t)(kt * 64 + nt * 16 + l15) * 64 + ks * 32 + quad * 8;
      gll16(khB + koff, Ksh + cb * 512);
      gll16(klB + koff, Ksl + cb * 512);
      gll16(vB + (size_t)(nt * 16 + l15) * 1024 + kt * 64 + ks * 32 + quad * 8, Vs + cb * 512);
    }
    __syncthreads();
    f32x4 s[4];
    #pragma unroll
    for (int nt = 0; nt < 4; nt++) s[nt] = f32x4{0.f, 0.f, 0.f, 0.f};
    #pragma unroll
    for (int ks = 0; ks < 2; ks++)
      #pragma unroll
      for (int nt = 0; nt < 4; nt++) {
        bf16x8 kfh = *(const bf16x8*)(Ksh + (ks * 4 + nt) * 512 + lane * 8);
        bf16x8 kfl = *(const bf16x8*)(Ksl + (ks * 4 + nt) * 512 + lane * 8);
        s[nt] = __builtin_amdgcn_mfma_f32_16x16x32_bf16(aqh[ks], kfh, s[nt], 0, 0, 0);
        s[nt] = __builtin_amdgcn_mfma_f32_16x16x32_bf16(aql[ks], kfh, s[nt], 0, 0, 0);
        s[nt] = __builtin_amdgcn_mfma_f32_16x16x32_bf16(aqh[ks], kfl, s[nt], 0, 0, 0);
      }
    float rmax[4];
    #pragma unroll
    for (int r = 0; r < 4; r++)
      rmax[r] = fmaxf(fmaxf(s[0][r], s[1][r]), fmaxf(s[2][r], s[3][r]));
    #pragma unroll
    for (int off = 1; off < 16; off <<= 1)
      #pragma unroll
      for (int r = 0; r < 4; r++)
        rmax[r] = fmaxf(rmax[r], __shfl_xor(rmax[r], off));
    float alpha[4], rsum[4];
    #pragma unroll
    for (int r = 0; r < 4; r++) {
      float mn = fmaxf(m_old[r], rmax[r]);
      alpha[r] = __expf(m_old[r] - mn);
      m_old[r] = mn;
      rsum[r] = 0.f;
    }
    #pragma unroll
    for (int nt = 0; nt < 4; nt++)
      #pragma unroll
      for (int r = 0; r < 4; r++) {
        float p = __expf(s[nt][r] - m_old[r]);
        rsum[r] += p;
        Ps[w][(quad * 4 + r) * 72 + nt * 16 + l15] = f2bf(p);
      }
    #pragma unroll
    for (int off = 1; off < 16; off <<= 1)
      #pragma unroll
      for (int r = 0; r < 4; r++)
        rsum[r] += __shfl_xor(rsum[r], off);
    #pragma unroll
    for (int r = 0; r < 4; r++) l_old[r] = l_old[r] * alpha[r] + rsum[r];
    #pragma unroll
    for (int nt = 0; nt < 4; nt++)
      #pragma unroll
      for (int r = 0; r < 4; r++) o[nt][r] *= alpha[r];
    #pragma unroll
    for (int ks = 0; ks < 2; ks++) {
      bf16x8 pa = *(const bf16x8*)(&Ps[w][l15 * 72 + ks * 32 + quad * 8]);
      #pragma unroll
      for (int nt = 0; nt < 4; nt++) {
        bf16x8 vf = *(const bf16x8*)(Vs + (ks * 4 + nt) * 512 + lane * 8);
        o[nt] = __builtin_amdgcn_mfma_f32_16x16x32_bf16(pa, vf, o[nt], 0, 0, 0);
      }
    }
    __syncthreads();
  }
  #pragma unroll
  for (int r = 0; r < 4; r++) {
    float inv = 1.f / l_old[r];
    int n = qt * 64 + w * 16 + quad * 4 + r;
    #pragma unroll
    for (int nt = 0; nt < 4; nt++)
      out[((size_t)(b_ * 1024 + n)) * 512 + h * 64 + nt * 16 + l15] = o[nt][r] * inv;
  }
}

// ----------------------------------------------------------------------- host
extern "C" void kernel_launch(void* const* d_in, const int* in_sizes, int n_in,
                              void* d_out, int out_size, void* d_ws, size_t ws_size,
                              hipStream_t stream) {
  const float* x  = (const float*)d_in[0];
  const float* Wq = (const float*)d_in[1];
  const float* bq = (const float*)d_in[2];
  const float* Wk = (const float*)d_in[3];
  const float* bk = (const float*)d_in[4];
  const float* Wv = (const float*)d_in[5];
  const float* bv = (const float*)d_in[6];
  const float* Wg = (const float*)d_in[7];
  const float* bg = (const float*)d_in[8];
  float* out = (float*)d_out;

  const size_t NX = (size_t)TOK * EDIM;        // 2M elems
  const size_t NWG = (size_t)GCOLS * EDIM;     // 16M elems
  const size_t NW = (size_t)EDIM * EDIM;       // 256K elems

  char* p = (char*)d_ws;
  u16* xh  = (u16*)p; p += NX * 2;
  u16* xl  = (u16*)p; p += NX * 2;
  u16* Wgh = (u16*)p; p += NWG * 2;
  u16* Wqh = (u16*)p; p += NW * 2;
  u16* Wql = (u16*)p; p += NW * 2;
  u16* Wkh = (u16*)p; p += NW * 2;
  u16* Wkl = (u16*)p; p += NW * 2;
  u16* Wvh = (u16*)p; p += NW * 2;
  u16* Wvl = (u16*)p; p += NW * 2;
  float* qf = (float*)p; p += NX * 4;
  u16* kh  = (u16*)p; p += NX * 2;
  u16* kl  = (u16*)p; p += NX * 2;
  u16* vT  = (u16*)p; p += NX * 2;
  u16* qgh = (u16*)p; p += NX * 2;
  u16* qgl = (u16*)p; p += NX * 2;
  size_t base_need = (size_t)(p - (char*)d_ws);
  // third g-pass needs Wg_lo (33.5 MB) — use it only if workspace allows
  bool g3 = ws_size >= base_need + NWG * 2;
  u16* Wgl = (u16*)p;  // only valid if g3

  hipLaunchKernelGGL(split_bf16_k, dim3(NX / 1024), dim3(256), 0, stream,
                     x, xh, xl, (int)NX);
  hipLaunchKernelGGL(transpose_split_k, dim3(EDIM / 32, EDIM / 32), dim3(32, 8), 0, stream,
                     Wq, Wqh, Wql, EDIM, EDIM);
  hipLaunchKernelGGL(transpose_split_k, dim3(EDIM / 32, EDIM / 32), dim3(32, 8), 0, stream,
                     Wk, Wkh, Wkl, EDIM, EDIM);
  hipLaunchKernelGGL(transpose_split_k, dim3(EDIM / 32, EDIM / 32), dim3(32, 8), 0, stream,
                     Wv, Wvh, Wvl, EDIM, EDIM);
  hipLaunchKernelGGL(transpose_split_k, dim3(GCOLS / 32, EDIM / 32), dim3(32, 8), 0, stream,
                     Wg, Wgh, g3 ? Wgl : (u16*)nullptr, EDIM, GCOLS);
  hipLaunchKernelGGL(qkv_gemm_k, dim3(TOK / 128, EDIM / 128, 3), dim3(256), 0, stream,
                     xh, xl, Wqh, Wql, Wkh, Wkl, Wvh, Wvl, bq, bk, bv, qf, kh, kl, vT);
  hipLaunchKernelGGL(qg_fused_k, dim3(256), dim3(512), 0, stream,
                     xh, xl, Wgh, g3 ? Wgl : (u16*)nullptr, bg, qf, qgh, qgl, g3 ? 3 : 2);
  hipLaunchKernelGGL(attn_k, dim3(512), dim3(256), 0, stream,
                     qgh, qgl, kh, kl, vT, out);
}

// Round 5
// 643.477 us; speedup vs baseline: 2.2716x; 2.2716x over previous
//
#include <hip/hip_runtime.h>
#include <math.h>

// Problem constants
#define TOK   4096    // B*N
#define EDIM  512
#define HEADS 8
#define DHEAD 64
#define GCOLS 32768   // H*D*D

typedef unsigned short u16;
typedef _Float16 f16;
typedef __attribute__((ext_vector_type(8))) f16 f16x8;      // 8 fp16 = 4 VGPRs (MFMA A/B frag)
typedef __attribute__((ext_vector_type(4))) float f32x4;    // MFMA C/D frag
typedef __attribute__((ext_vector_type(4))) unsigned short u16x4;

typedef const __attribute__((address_space(1))) void* gas_ptr;
typedef __attribute__((address_space(3))) void* las_ptr;

__device__ __forceinline__ void gll16(const void* g, void* lds) {
  // async global->LDS, 16B/lane: per-lane global addr, wave-uniform LDS base,
  // lane i lands at lds + i*16
  __builtin_amdgcn_global_load_lds((gas_ptr)g, (las_ptr)lds, 16, 0, 0);
}

__device__ __forceinline__ u16 f2h_bits(float f) {
  union { f16 h; u16 u; } v; v.h = (f16)f;   // RNE
  return v.u;
}
__device__ __forceinline__ float gelu_exact(float x) {
  return 0.5f * x * (1.0f + erff(x * 0.7071067811865475f));
}

// ---------------------------------------------------------------- cast x -> fp16
__global__ void cast_f16_k(const float* __restrict__ in, u16* __restrict__ out, int n) {
  int i = (blockIdx.x * blockDim.x + threadIdx.x) * 4;
  if (i + 3 < n) {
    float4 f = *(const float4*)(in + i);
    u16x4 h;
    h.x = f2h_bits(f.x); h.y = f2h_bits(f.y);
    h.z = f2h_bits(f.z); h.w = f2h_bits(f.w);
    *(u16x4*)(out + i) = h;
  }
}

// -------------------- transpose W[K][N] -> Wt[N][K] fp16
__global__ void transpose_f16_k(const float* __restrict__ in, u16* __restrict__ out,
                                int K, int N) {
  __shared__ float tile[32][33];
  int n0 = blockIdx.x * 32, k0 = blockIdx.y * 32;
  int tx = threadIdx.x, ty = threadIdx.y;  // (32,8)
  #pragma unroll
  for (int i = 0; i < 4; i++)
    tile[ty + i * 8][tx] = in[(size_t)(k0 + ty + i * 8) * N + n0 + tx];
  __syncthreads();
  #pragma unroll
  for (int i = 0; i < 4; i++)
    out[(size_t)(n0 + ty + i * 8) * K + k0 + tx] = f2h_bits(tile[tx][ty + i * 8]);
}

// ---------------------------------------------------------------- QKV GEMM
// 128x128 tile, BK=64, 4 waves (each 64x64), single-pass fp16 MFMA.
// q stored fp32 [B][H][N][D]; k fp16 [B][H][N][D]; v transposed fp16 [B][H][D][N].
__global__ __launch_bounds__(256, 2) void qkv_gemm_k(
    const u16* __restrict__ xf, const u16* __restrict__ Wqt,
    const u16* __restrict__ Wkt, const u16* __restrict__ Wvt,
    const float* __restrict__ bq, const float* __restrict__ bk, const float* __restrict__ bv,
    float* __restrict__ qf, u16* __restrict__ ko, u16* __restrict__ vTo) {
  __shared__ __align__(16) u16 As[16 * 512];
  __shared__ __align__(16) u16 Bs[16 * 512];
  const int which = blockIdx.z;
  const u16* Wt = which == 0 ? Wqt : (which == 1 ? Wkt : Wvt);
  const float* bias = which == 0 ? bq : (which == 1 ? bk : bv);
  const int m0 = blockIdx.x * 128;
  const int n0 = blockIdx.y * 128;
  const int tid = threadIdx.x;
  const int w = tid >> 6, lane = tid & 63, l15 = lane & 15, quad = lane >> 4;
  const int mhalf = w >> 1, nhalf = w & 1;

  f32x4 acc[4][4];
  #pragma unroll
  for (int i = 0; i < 4; i++)
    #pragma unroll
    for (int j = 0; j < 4; j++) acc[i][j] = f32x4{0.f, 0.f, 0.f, 0.f};

  for (int kk = 0; kk < 512; kk += 64) {
    #pragma unroll
    for (int i = 0; i < 8; i++) {
      int cb = w * 8 + i;
      if (cb < 16) {
        int ks = cb >> 3, mt = cb & 7;
        gll16(xf + (size_t)(m0 + mt * 16 + l15) * 512 + kk + ks * 32 + quad * 8,
              As + cb * 512);
      } else {
        int bi = cb - 16, ks = bi >> 3, nt = bi & 7;
        gll16(Wt + (size_t)(n0 + nt * 16 + l15) * 512 + kk + ks * 32 + quad * 8,
              Bs + bi * 512);
      }
    }
    __syncthreads();
    #pragma unroll
    for (int ks = 0; ks < 2; ks++) {
      f16x8 a[4], b[4];
      #pragma unroll
      for (int mt = 0; mt < 4; mt++)
        a[mt] = *(const f16x8*)(As + (ks * 8 + mhalf * 4 + mt) * 512 + lane * 8);
      #pragma unroll
      for (int nt = 0; nt < 4; nt++)
        b[nt] = *(const f16x8*)(Bs + (ks * 8 + nhalf * 4 + nt) * 512 + lane * 8);
      #pragma unroll
      for (int mt = 0; mt < 4; mt++)
        #pragma unroll
        for (int nt = 0; nt < 4; nt++)
          acc[mt][nt] = __builtin_amdgcn_mfma_f32_16x16x32_f16(a[mt], b[nt], acc[mt][nt], 0, 0, 0);
    }
    __syncthreads();
  }
  #pragma unroll
  for (int nt = 0; nt < 4; nt++) {
    int col = n0 + (nhalf * 4 + nt) * 16 + l15;
    float bia = bias[col];
    int h = col >> 6, d = col & 63;
    #pragma unroll
    for (int mt = 0; mt < 4; mt++) {
      #pragma unroll
      for (int r = 0; r < 4; r++) {
        int t = m0 + (mhalf * 4 + mt) * 16 + quad * 4 + r;
        int b_ = t >> 10, n = t & 1023;
        float val = acc[mt][nt][r] + bia;
        size_t idx = (((size_t)(b_ * 8 + h) * 1024) + n) * 64 + d;
        if (which == 0)      qf[idx] = val;
        else if (which == 1) ko[idx] = f2h_bits(val);
        else                 vTo[(((size_t)(b_ * 8 + h) * 64) + d) * 1024 + n] = f2h_bits(val);
      }
    }
  }
}

// ---------------------------------------------------------------- fused g-GEMM + q.g
// Block = 128 tokens x one head x half the d-range (16 j-chunks), 512 threads (8 waves).
// Grid 512 -> 2 blocks/CU so barrier drains overlap across blocks.
// q kept fp32; qg written as fp32 PARTIAL (summed in attn_k).
// Partial stride = TOK*EDIM elems (full [B][H][N][D] tensor = 2M elems).
__global__ __launch_bounds__(512, 2) void qg_fused_k(
    const u16* __restrict__ xf, const u16* __restrict__ Wgt,
    const float* __restrict__ bg, const float* __restrict__ qf,
    float* __restrict__ qgp) {
  __shared__ __align__(16) u16 As[16 * 512];   // 16KB
  __shared__ __align__(16) u16 Bs[16 * 512];   // 16KB
  __shared__ __align__(16) float Qs[128 * 64]; // 32KB fp32 q rows
  const int head = blockIdx.x & 7;             // XCD-pinned per head
  const int jh = (blockIdx.x >> 3) & 1;        // which half of the d-range
  const int t0 = (blockIdx.x >> 4) * 128;
  const int tid = threadIdx.x;
  const int w = tid >> 6, lane = tid & 63, l15 = lane & 15, quad = lane >> 4;
  const int mhalf = w >> 2;   // 0..1  (token half)
  const int ntA = w & 3;      // 0..3  (e-range /16)
  const int b_ = t0 >> 10, nseq0 = t0 & 1023;
  const float* qbase = qf + (((size_t)(b_ * 8 + head) * 1024) + nseq0) * 64;

  // stage Qs (contiguous 32KB fp32); global addr per-lane (+lane*16)
  #pragma unroll
  for (int i = 0; i < 4; i++) {
    int cb = w * 4 + i;
    gll16((const char*)qbase + (size_t)cb * 1024 + (size_t)lane * 16,
          (char*)Qs + (size_t)cb * 1024);
  }
  f32x4 qg[4];
  #pragma unroll
  for (int i = 0; i < 4; i++) qg[i] = f32x4{0.f, 0.f, 0.f, 0.f};
  __syncthreads();

  for (int jj = 0; jj < 16; jj++) {
    const int j = jh * 16 + jj;
    f32x4 zacc[4][2];
    #pragma unroll
    for (int i = 0; i < 4; i++) {
      zacc[i][0] = f32x4{0.f, 0.f, 0.f, 0.f};
      zacc[i][1] = f32x4{0.f, 0.f, 0.f, 0.f};
    }
    const int c0 = head * 4096 + j * 128;
    for (int kk = 0; kk < 512; kk += 64) {
      #pragma unroll
      for (int i = 0; i < 4; i++) {
        int cb = w * 4 + i;
        if (cb < 16) {
          int ks = cb >> 3, mt = cb & 7;
          gll16(xf + (size_t)(t0 + mt * 16 + l15) * 512 + kk + ks * 32 + quad * 8,
                As + cb * 512);
        } else {
          int bi = cb - 16, ks = bi >> 3, nt = bi & 7;
          gll16(Wgt + (size_t)(c0 + nt * 16 + l15) * 512 + kk + ks * 32 + quad * 8,
                Bs + bi * 512);
        }
      }
      __syncthreads();
      #pragma unroll
      for (int ks = 0; ks < 2; ks++) {
        f16x8 a[4];
        #pragma unroll
        for (int mt = 0; mt < 4; mt++)
          a[mt] = *(const f16x8*)(As + (ks * 8 + mhalf * 4 + mt) * 512 + lane * 8);
        f16x8 b0 = *(const f16x8*)(Bs + (ks * 8 + ntA) * 512 + lane * 8);
        f16x8 b1 = *(const f16x8*)(Bs + (ks * 8 + ntA + 4) * 512 + lane * 8);
        #pragma unroll
        for (int mt = 0; mt < 4; mt++) {
          zacc[mt][0] = __builtin_amdgcn_mfma_f32_16x16x32_f16(a[mt], b0, zacc[mt][0], 0, 0, 0);
          zacc[mt][1] = __builtin_amdgcn_mfma_f32_16x16x32_f16(a[mt], b1, zacc[mt][1], 0, 0, 0);
        }
      }
      __syncthreads();
    }
    // epilogue: bias + exact gelu + contract with fp32 q over d=2j, 2j+1
    float bg0 = bg[c0 + ntA * 16 + l15];
    float bg1 = bg[c0 + (ntA + 4) * 16 + l15];
    #pragma unroll
    for (int mt = 0; mt < 4; mt++) {
      #pragma unroll
      for (int r = 0; r < 4; r++) {
        int row = mhalf * 64 + mt * 16 + quad * 4 + r;
        float2 qp = *(const float2*)&Qs[row * 64 + 2 * j];
        float g0 = gelu_exact(zacc[mt][0][r] + bg0);
        float g1 = gelu_exact(zacc[mt][1][r] + bg1);
        qg[mt][r] += qp.x * g0 + qp.y * g1;
      }
    }
  }
  float* qout = qgp + (size_t)jh * TOK * EDIM;   // FIX: partial stride = 2M elems
  const int eb = ntA * 16;
  #pragma unroll
  for (int mt = 0; mt < 4; mt++) {
    #pragma unroll
    for (int r = 0; r < 4; r++) {
      int t = t0 + mhalf * 64 + mt * 16 + quad * 4 + r;
      int bb = t >> 10, n = t & 1023;
      qout[(((size_t)(bb * 8 + head) * 1024) + n) * 64 + eb + l15] = qg[mt][r];
    }
  }
}

// ---------------------------------------------------------------- flash attention
// Block = (b,h,qtile64), 4 waves x 16 q-rows. qg = partial0+partial1 (fp32->fp16),
// S = qg@k^T fp16 MFMA, online softmax, P->LDS (C->A layout turn), O += P@V.
__global__ __launch_bounds__(256, 2) void attn_k(
    const float* __restrict__ qgp, const u16* __restrict__ kb,
    const u16* __restrict__ vTb, float* __restrict__ out) {
  __shared__ __align__(16) u16 Ks[8 * 512];
  __shared__ __align__(16) u16 Vs[8 * 512];
  __shared__ __align__(16) f16 Ps[4][16 * 72];    // per-wave P, row stride 72
  const int idx = blockIdx.x;
  const int bh = idx & 31;   // b*8+h -> XCD = bh%8
  const int qt = idx >> 5;
  const int b_ = bh >> 3, h = bh & 7;
  const int tid = threadIdx.x;
  const int w = tid >> 6, lane = tid & 63, l15 = lane & 15, quad = lane >> 4;

  const float* qg0 = qgp + (size_t)bh * 1024 * 64;
  const float* qg1 = qg0 + (size_t)TOK * EDIM;   // FIX: partial stride = 2M elems
  const u16* kB  = kb  + (size_t)bh * 1024 * 64;
  const u16* vB  = vTb + (size_t)bh * 64 * 1024;

  f16x8 aq[2];
  #pragma unroll
  for (int ks = 0; ks < 2; ks++) {
    size_t off = (size_t)(qt * 64 + w * 16 + l15) * 64 + ks * 32 + quad * 8;
    f16x8 v;
    #pragma unroll
    for (int e = 0; e < 8; e++)
      v[e] = (f16)(qg0[off + e] + qg1[off + e]);
    aq[ks] = v;
  }

  f32x4 o[4];
  #pragma unroll
  for (int i = 0; i < 4; i++) o[i] = f32x4{0.f, 0.f, 0.f, 0.f};
  float m_old[4], l_old[4];
  #pragma unroll
  for (int r = 0; r < 4; r++) { m_old[r] = -1e30f; l_old[r] = 0.f; }

  for (int kt = 0; kt < 16; kt++) {
    #pragma unroll
    for (int i = 0; i < 2; i++) {
      int cb = w * 2 + i;
      int ks = cb >> 2, nt = cb & 3;
      gll16(kB + (size_t)(kt * 64 + nt * 16 + l15) * 64 + ks * 32 + quad * 8, Ks + cb * 512);
      gll16(vB + (size_t)(nt * 16 + l15) * 1024 + kt * 64 + ks * 32 + quad * 8, Vs + cb * 512);
    }
    __syncthreads();
    f32x4 s[4];
    #pragma unroll
    for (int nt = 0; nt < 4; nt++) s[nt] = f32x4{0.f, 0.f, 0.f, 0.f};
    #pragma unroll
    for (int ks = 0; ks < 2; ks++)
      #pragma unroll
      for (int nt = 0; nt < 4; nt++) {
        f16x8 kf = *(const f16x8*)(Ks + (ks * 4 + nt) * 512 + lane * 8);
        s[nt] = __builtin_amdgcn_mfma_f32_16x16x32_f16(aq[ks], kf, s[nt], 0, 0, 0);
      }
    float rmax[4];
    #pragma unroll
    for (int r = 0; r < 4; r++)
      rmax[r] = fmaxf(fmaxf(s[0][r], s[1][r]), fmaxf(s[2][r], s[3][r]));
    #pragma unroll
    for (int off = 1; off < 16; off <<= 1)
      #pragma unroll
      for (int r = 0; r < 4; r++)
        rmax[r] = fmaxf(rmax[r], __shfl_xor(rmax[r], off));
    float alpha[4], rsum[4];
    #pragma unroll
    for (int r = 0; r < 4; r++) {
      float mn = fmaxf(m_old[r], rmax[r]);
      alpha[r] = __expf(m_old[r] - mn);
      m_old[r] = mn;
      rsum[r] = 0.f;
    }
    #pragma unroll
    for (int nt = 0; nt < 4; nt++)
      #pragma unroll
      for (int r = 0; r < 4; r++) {
        float p = __expf(s[nt][r] - m_old[r]);
        rsum[r] += p;
        Ps[w][(quad * 4 + r) * 72 + nt * 16 + l15] = (f16)p;
      }
    #pragma unroll
    for (int off = 1; off < 16; off <<= 1)
      #pragma unroll
      for (int r = 0; r < 4; r++)
        rsum[r] += __shfl_xor(rsum[r], off);
    #pragma unroll
    for (int r = 0; r < 4; r++) l_old[r] = l_old[r] * alpha[r] + rsum[r];
    #pragma unroll
    for (int nt = 0; nt < 4; nt++)
      #pragma unroll
      for (int r = 0; r < 4; r++) o[nt][r] *= alpha[r];
    #pragma unroll
    for (int ks = 0; ks < 2; ks++) {
      f16x8 pa = *(const f16x8*)(&Ps[w][l15 * 72 + ks * 32 + quad * 8]);
      #pragma unroll
      for (int nt = 0; nt < 4; nt++) {
        f16x8 vf = *(const f16x8*)(Vs + (ks * 4 + nt) * 512 + lane * 8);
        o[nt] = __builtin_amdgcn_mfma_f32_16x16x32_f16(pa, vf, o[nt], 0, 0, 0);
      }
    }
    __syncthreads();
  }
  #pragma unroll
  for (int r = 0; r < 4; r++) {
    float inv = 1.f / l_old[r];
    int n = qt * 64 + w * 16 + quad * 4 + r;
    #pragma unroll
    for (int nt = 0; nt < 4; nt++)
      out[((size_t)(b_ * 1024 + n)) * 512 + h * 64 + nt * 16 + l15] = o[nt][r] * inv;
  }
}

// ----------------------------------------------------------------------- host
extern "C" void kernel_launch(void* const* d_in, const int* in_sizes, int n_in,
                              void* d_out, int out_size, void* d_ws, size_t ws_size,
                              hipStream_t stream) {
  const float* x  = (const float*)d_in[0];
  const float* Wq = (const float*)d_in[1];
  const float* bq = (const float*)d_in[2];
  const float* Wk = (const float*)d_in[3];
  const float* bk = (const float*)d_in[4];
  const float* Wv = (const float*)d_in[5];
  const float* bv = (const float*)d_in[6];
  const float* Wg = (const float*)d_in[7];
  const float* bg = (const float*)d_in[8];
  float* out = (float*)d_out;

  const size_t NX = (size_t)TOK * EDIM;        // 2M elems
  const size_t NWG = (size_t)GCOLS * EDIM;     // 16.8M elems
  const size_t NW = (size_t)EDIM * EDIM;       // 256K elems

  char* p = (char*)d_ws;
  u16* xf  = (u16*)p; p += NX * 2;             // x fp16
  u16* Wgt = (u16*)p; p += NWG * 2;            // Wg^T fp16 (33.5 MB)
  u16* Wqt = (u16*)p; p += NW * 2;
  u16* Wkt = (u16*)p; p += NW * 2;
  u16* Wvt = (u16*)p; p += NW * 2;
  float* qf = (float*)p; p += NX * 4;          // q fp32 [B][H][N][D]
  u16* kf  = (u16*)p; p += NX * 2;             // k fp16
  u16* vT  = (u16*)p; p += NX * 2;             // v^T fp16
  float* qgp = (float*)p; p += NX * 4 * 2;     // qg fp32 partials [2][B][H][N][D]

  hipLaunchKernelGGL(cast_f16_k, dim3(NX / 1024), dim3(256), 0, stream,
                     x, xf, (int)NX);
  hipLaunchKernelGGL(transpose_f16_k, dim3(EDIM / 32, EDIM / 32), dim3(32, 8), 0, stream,
                     Wq, Wqt, EDIM, EDIM);
  hipLaunchKernelGGL(transpose_f16_k, dim3(EDIM / 32, EDIM / 32), dim3(32, 8), 0, stream,
                     Wk, Wkt, EDIM, EDIM);
  hipLaunchKernelGGL(transpose_f16_k, dim3(EDIM / 32, EDIM / 32), dim3(32, 8), 0, stream,
                     Wv, Wvt, EDIM, EDIM);
  hipLaunchKernelGGL(transpose_f16_k, dim3(GCOLS / 32, EDIM / 32), dim3(32, 8), 0, stream,
                     Wg, Wgt, EDIM, GCOLS);
  hipLaunchKernelGGL(qkv_gemm_k, dim3(TOK / 128, EDIM / 128, 3), dim3(256), 0, stream,
                     xf, Wqt, Wkt, Wvt, bq, bk, bv, qf, kf, vT);
  hipLaunchKernelGGL(qg_fused_k, dim3(512), dim3(512), 0, stream,
                     xf, Wgt, bg, qf, qgp);
  hipLaunchKernelGGL(attn_k, dim3(512), dim3(256), 0, stream,
                     qgp, kf, vT, out);
}

// Round 6
// 481.792 us; speedup vs baseline: 3.0339x; 1.3356x over previous
//
#include <hip/hip_runtime.h>
#include <math.h>

// Problem constants
#define TOK   4096    // B*N
#define EDIM  512
#define HEADS 8
#define DHEAD 64
#define GCOLS 32768   // H*D*D

typedef unsigned short u16;
typedef _Float16 f16;
typedef __attribute__((ext_vector_type(8))) f16 f16x8;      // 8 fp16 = 4 VGPRs (MFMA A/B frag)
typedef __attribute__((ext_vector_type(4))) f16 f16x4;
typedef __attribute__((ext_vector_type(4))) float f32x4;    // MFMA C/D frag
typedef __attribute__((ext_vector_type(4))) unsigned short u16x4;

typedef const __attribute__((address_space(1))) void* gas_ptr;
typedef __attribute__((address_space(3))) void* las_ptr;

__device__ __forceinline__ void gll16(const void* g, void* lds) {
  // async global->LDS, 16B/lane: per-lane global addr, wave-uniform LDS base,
  // lane i lands at lds + i*16
  __builtin_amdgcn_global_load_lds((gas_ptr)g, (las_ptr)lds, 16, 0, 0);
}

__device__ __forceinline__ u16 f2h_bits(float f) {
  union { f16 h; u16 u; } v; v.h = (f16)f;   // RNE
  return v.u;
}

// Abramowitz-Stegun 7.1.26 erf: |abs err| <= 1.5e-7, ~15 VALU insts
// (libm erff measured ~80 insts -> VALUBusy 28% in R5; this is the fix)
__device__ __forceinline__ float fast_gelu(float x) {
  float s = x * 0.7071067811865475f;
  float ax = fabsf(s);
  float t = 1.0f / (1.0f + 0.3275911f * ax);
  float poly = t * (0.254829592f + t * (-0.284496736f + t * (1.421413741f +
               t * (-1.453152027f + t * 1.061405429f))));
  float e = __expf(-ax * ax);
  float r = 1.0f - poly * e;
  float erfv = copysignf(r, s);
  return 0.5f * x * (1.0f + erfv);
}

// ---------------------------------------------------------------- cast x -> fp16
__global__ void cast_f16_k(const float* __restrict__ in, u16* __restrict__ out, int n) {
  int i = (blockIdx.x * blockDim.x + threadIdx.x) * 4;
  if (i + 3 < n) {
    float4 f = *(const float4*)(in + i);
    u16x4 h;
    h.x = f2h_bits(f.x); h.y = f2h_bits(f.y);
    h.z = f2h_bits(f.z); h.w = f2h_bits(f.w);
    *(u16x4*)(out + i) = h;
  }
}

// -------------------- transpose W[K][N] -> Wt[N][K] fp16
__global__ void transpose_f16_k(const float* __restrict__ in, u16* __restrict__ out,
                                int K, int N) {
  __shared__ float tile[32][33];
  int n0 = blockIdx.x * 32, k0 = blockIdx.y * 32;
  int tx = threadIdx.x, ty = threadIdx.y;  // (32,8)
  #pragma unroll
  for (int i = 0; i < 4; i++)
    tile[ty + i * 8][tx] = in[(size_t)(k0 + ty + i * 8) * N + n0 + tx];
  __syncthreads();
  #pragma unroll
  for (int i = 0; i < 4; i++)
    out[(size_t)(n0 + ty + i * 8) * K + k0 + tx] = f2h_bits(tile[tx][ty + i * 8]);
}

// ---------------------------------------------------------------- QKV GEMM
// 128x128 tile, BK=64, 4 waves (each 64x64), single-pass fp16 MFMA.
// q fp16 [B][H][N][D]; k fp16 [B][H][N][D]; v transposed fp16 [B][H][D][N].
__global__ __launch_bounds__(256, 2) void qkv_gemm_k(
    const u16* __restrict__ xf, const u16* __restrict__ Wqt,
    const u16* __restrict__ Wkt, const u16* __restrict__ Wvt,
    const float* __restrict__ bq, const float* __restrict__ bk, const float* __restrict__ bv,
    u16* __restrict__ qho, u16* __restrict__ ko, u16* __restrict__ vTo) {
  __shared__ __align__(16) u16 As[16 * 512];
  __shared__ __align__(16) u16 Bs[16 * 512];
  const int which = blockIdx.z;
  const u16* Wt = which == 0 ? Wqt : (which == 1 ? Wkt : Wvt);
  const float* bias = which == 0 ? bq : (which == 1 ? bk : bv);
  const int m0 = blockIdx.x * 128;
  const int n0 = blockIdx.y * 128;
  const int tid = threadIdx.x;
  const int w = tid >> 6, lane = tid & 63, l15 = lane & 15, quad = lane >> 4;
  const int mhalf = w >> 1, nhalf = w & 1;

  f32x4 acc[4][4];
  #pragma unroll
  for (int i = 0; i < 4; i++)
    #pragma unroll
    for (int j = 0; j < 4; j++) acc[i][j] = f32x4{0.f, 0.f, 0.f, 0.f};

  for (int kk = 0; kk < 512; kk += 64) {
    #pragma unroll
    for (int i = 0; i < 8; i++) {
      int cb = w * 8 + i;
      if (cb < 16) {
        int ks = cb >> 3, mt = cb & 7;
        gll16(xf + (size_t)(m0 + mt * 16 + l15) * 512 + kk + ks * 32 + quad * 8,
              As + cb * 512);
      } else {
        int bi = cb - 16, ks = bi >> 3, nt = bi & 7;
        gll16(Wt + (size_t)(n0 + nt * 16 + l15) * 512 + kk + ks * 32 + quad * 8,
              Bs + bi * 512);
      }
    }
    __syncthreads();
    #pragma unroll
    for (int ks = 0; ks < 2; ks++) {
      f16x8 a[4], b[4];
      #pragma unroll
      for (int mt = 0; mt < 4; mt++)
        a[mt] = *(const f16x8*)(As + (ks * 8 + mhalf * 4 + mt) * 512 + lane * 8);
      #pragma unroll
      for (int nt = 0; nt < 4; nt++)
        b[nt] = *(const f16x8*)(Bs + (ks * 8 + nhalf * 4 + nt) * 512 + lane * 8);
      #pragma unroll
      for (int mt = 0; mt < 4; mt++)
        #pragma unroll
        for (int nt = 0; nt < 4; nt++)
          acc[mt][nt] = __builtin_amdgcn_mfma_f32_16x16x32_f16(a[mt], b[nt], acc[mt][nt], 0, 0, 0);
    }
    __syncthreads();
  }
  #pragma unroll
  for (int nt = 0; nt < 4; nt++) {
    int col = n0 + (nhalf * 4 + nt) * 16 + l15;
    float bia = bias[col];
    int h = col >> 6, d = col & 63;
    #pragma unroll
    for (int mt = 0; mt < 4; mt++) {
      #pragma unroll
      for (int r = 0; r < 4; r++) {
        int t = m0 + (mhalf * 4 + mt) * 16 + quad * 4 + r;
        int b_ = t >> 10, n = t & 1023;
        float val = acc[mt][nt][r] + bia;
        size_t idx = (((size_t)(b_ * 8 + h) * 1024) + n) * 64 + d;
        if (which == 0)      qho[idx] = f2h_bits(val);
        else if (which == 1) ko[idx] = f2h_bits(val);
        else                 vTo[(((size_t)(b_ * 8 + h) * 64) + d) * 1024 + n] = f2h_bits(val);
      }
    }
  }
}

// ---------------------------------------------------------------- fused g-GEMM + q.g
// Block = 128 tokens x one head x half the d-range, 512 threads (8 waves).
// j-PAIR merge: per stage, one As (x-tile, shared by both j) + 256 cols of Wg.
// 8 jp x 8 kk = 64 stages (was 128). LDS = As 16K + Bs 32K + Qs 16K = 64KB
// -> 2 blocks/CU. Wave (mhalf, ntA) owns 64 tokens x e-range ntA*16..+15 for
// all 4 d of the pair -> private qg accumulator, no reduction.
// Partial stride = TOK*EDIM elems (full [B][H][N][D] tensor).
__global__ __launch_bounds__(512, 4) void qg_fused_k(
    const u16* __restrict__ xf, const u16* __restrict__ Wgt,
    const float* __restrict__ bg, const u16* __restrict__ qh,
    float* __restrict__ qgp) {
  __shared__ __align__(16) u16 As[16 * 512];   // 16KB: 128 tok x 64 K
  __shared__ __align__(16) u16 Bs[32 * 512];   // 32KB: 256 cols x 64 K
  __shared__ __align__(16) u16 Qs[128 * 64];   // 16KB: q fp16 rows
  const int head = blockIdx.x & 7;             // XCD-pinned per head
  const int jh = (blockIdx.x >> 3) & 1;        // which half of the d-range
  const int t0 = (blockIdx.x >> 4) * 128;
  const int tid = threadIdx.x;
  const int w = tid >> 6, lane = tid & 63, l15 = lane & 15, quad = lane >> 4;
  const int mhalf = w >> 2;   // 0..1  (token half)
  const int ntA = w & 3;      // 0..3  (e-range /16)
  const int b_ = t0 >> 10, nseq0 = t0 & 1023;
  const u16* qbase = qh + (((size_t)(b_ * 8 + head) * 1024) + nseq0) * 64;

  // stage Qs (contiguous 16KB fp16); global addr per-lane (+lane*16B = lane*8 elems)
  #pragma unroll
  for (int i = 0; i < 2; i++) {
    int cb = w * 2 + i;
    gll16(qbase + (size_t)cb * 512 + (size_t)lane * 8, Qs + (size_t)cb * 512);
  }
  f32x4 qg[4];
  #pragma unroll
  for (int i = 0; i < 4; i++) qg[i] = f32x4{0.f, 0.f, 0.f, 0.f};
  __syncthreads();

  for (int jp = 0; jp < 8; jp++) {
    const int j0 = jh * 16 + jp * 2;              // pair = (j0, j0+1)
    const int c0 = head * 4096 + j0 * 128;        // 256 contiguous cols
    f32x4 zacc[4][4];                             // [mt][z]: z = j0d0,j0d1,j1d0,j1d1
    #pragma unroll
    for (int i = 0; i < 4; i++)
      #pragma unroll
      for (int z = 0; z < 4; z++) zacc[i][z] = f32x4{0.f, 0.f, 0.f, 0.f};

    for (int kk = 0; kk < 512; kk += 64) {
      // 48 fragment blocks: As 16 (ks*8+mt) + Bs 32 (ks*16+nt), 6 per wave
      #pragma unroll
      for (int i = 0; i < 6; i++) {
        int cb = w * 6 + i;
        if (cb < 16) {
          int ks = cb >> 3, mt = cb & 7;
          gll16(xf + (size_t)(t0 + mt * 16 + l15) * 512 + kk + ks * 32 + quad * 8,
                As + cb * 512);
        } else {
          int bi = cb - 16, ks = bi >> 4, nt = bi & 15;
          gll16(Wgt + (size_t)(c0 + nt * 16 + l15) * 512 + kk + ks * 32 + quad * 8,
                Bs + bi * 512);
        }
      }
      __syncthreads();
      #pragma unroll
      for (int ks = 0; ks < 2; ks++) {
        f16x8 a[4];
        #pragma unroll
        for (int mt = 0; mt < 4; mt++)
          a[mt] = *(const f16x8*)(As + (ks * 8 + mhalf * 4 + mt) * 512 + lane * 8);
        #pragma unroll
        for (int z = 0; z < 4; z++) {
          int nt = (z >> 1) * 8 + (z & 1) * 4 + ntA;
          f16x8 b = *(const f16x8*)(Bs + (ks * 16 + nt) * 512 + lane * 8);
          #pragma unroll
          for (int mt = 0; mt < 4; mt++)
            zacc[mt][z] = __builtin_amdgcn_mfma_f32_16x16x32_f16(a[mt], b, zacc[mt][z], 0, 0, 0);
        }
      }
      __syncthreads();
    }
    // epilogue: bias + fast gelu + contract with fp16 q over d = 2j0..2j0+3
    float bgv[4];
    #pragma unroll
    for (int z = 0; z < 4; z++) {
      int nt = (z >> 1) * 8 + (z & 1) * 4 + ntA;
      bgv[z] = bg[c0 + nt * 16 + l15];
    }
    const int d0 = 2 * j0;
    #pragma unroll
    for (int mt = 0; mt < 4; mt++) {
      #pragma unroll
      for (int r = 0; r < 4; r++) {
        int row = mhalf * 64 + mt * 16 + quad * 4 + r;
        f16x4 qp = *(const f16x4*)(Qs + row * 64 + d0);  // q[row][2j0..2j0+3]
        float g0 = fast_gelu(zacc[mt][0][r] + bgv[0]);
        float g1 = fast_gelu(zacc[mt][1][r] + bgv[1]);
        float g2 = fast_gelu(zacc[mt][2][r] + bgv[2]);
        float g3 = fast_gelu(zacc[mt][3][r] + bgv[3]);
        qg[mt][r] += (float)qp.x * g0 + (float)qp.y * g1 +
                     (float)qp.z * g2 + (float)qp.w * g3;
      }
    }
  }
  float* qout = qgp + (size_t)jh * TOK * EDIM;   // partial stride = 2M elems
  const int eb = ntA * 16;
  #pragma unroll
  for (int mt = 0; mt < 4; mt++) {
    #pragma unroll
    for (int r = 0; r < 4; r++) {
      int t = t0 + mhalf * 64 + mt * 16 + quad * 4 + r;
      int bb = t >> 10, n = t & 1023;
      qout[(((size_t)(bb * 8 + head) * 1024) + n) * 64 + eb + l15] = qg[mt][r];
    }
  }
}

// ---------------------------------------------------------------- flash attention
// Block = (b,h,qtile64), 4 waves x 16 q-rows. qg = partial0+partial1 (fp32->fp16),
// S = qg@k^T fp16 MFMA, online softmax, P->LDS (C->A layout turn), O += P@V.
__global__ __launch_bounds__(256, 2) void attn_k(
    const float* __restrict__ qgp, const u16* __restrict__ kb,
    const u16* __restrict__ vTb, float* __restrict__ out) {
  __shared__ __align__(16) u16 Ks[8 * 512];
  __shared__ __align__(16) u16 Vs[8 * 512];
  __shared__ __align__(16) f16 Ps[4][16 * 72];    // per-wave P, row stride 72
  const int idx = blockIdx.x;
  const int bh = idx & 31;   // b*8+h -> XCD = bh%8
  const int qt = idx >> 5;
  const int b_ = bh >> 3, h = bh & 7;
  const int tid = threadIdx.x;
  const int w = tid >> 6, lane = tid & 63, l15 = lane & 15, quad = lane >> 4;

  const float* qg0 = qgp + (size_t)bh * 1024 * 64;
  const float* qg1 = qg0 + (size_t)TOK * EDIM;   // partial stride = 2M elems
  const u16* kB  = kb  + (size_t)bh * 1024 * 64;
  const u16* vB  = vTb + (size_t)bh * 64 * 1024;

  f16x8 aq[2];
  #pragma unroll
  for (int ks = 0; ks < 2; ks++) {
    size_t off = (size_t)(qt * 64 + w * 16 + l15) * 64 + ks * 32 + quad * 8;
    f16x8 v;
    #pragma unroll
    for (int e = 0; e < 8; e++)
      v[e] = (f16)(qg0[off + e] + qg1[off + e]);
    aq[ks] = v;
  }

  f32x4 o[4];
  #pragma unroll
  for (int i = 0; i < 4; i++) o[i] = f32x4{0.f, 0.f, 0.f, 0.f};
  float m_old[4], l_old[4];
  #pragma unroll
  for (int r = 0; r < 4; r++) { m_old[r] = -1e30f; l_old[r] = 0.f; }

  for (int kt = 0; kt < 16; kt++) {
    #pragma unroll
    for (int i = 0; i < 2; i++) {
      int cb = w * 2 + i;
      int ks = cb >> 2, nt = cb & 3;
      gll16(kB + (size_t)(kt * 64 + nt * 16 + l15) * 64 + ks * 32 + quad * 8, Ks + cb * 512);
      gll16(vB + (size_t)(nt * 16 + l15) * 1024 + kt * 64 + ks * 32 + quad * 8, Vs + cb * 512);
    }
    __syncthreads();
    f32x4 s[4];
    #pragma unroll
    for (int nt = 0; nt < 4; nt++) s[nt] = f32x4{0.f, 0.f, 0.f, 0.f};
    #pragma unroll
    for (int ks = 0; ks < 2; ks++)
      #pragma unroll
      for (int nt = 0; nt < 4; nt++) {
        f16x8 kf = *(const f16x8*)(Ks + (ks * 4 + nt) * 512 + lane * 8);
        s[nt] = __builtin_amdgcn_mfma_f32_16x16x32_f16(aq[ks], kf, s[nt], 0, 0, 0);
      }
    float rmax[4];
    #pragma unroll
    for (int r = 0; r < 4; r++)
      rmax[r] = fmaxf(fmaxf(s[0][r], s[1][r]), fmaxf(s[2][r], s[3][r]));
    #pragma unroll
    for (int off = 1; off < 16; off <<= 1)
      #pragma unroll
      for (int r = 0; r < 4; r++)
        rmax[r] = fmaxf(rmax[r], __shfl_xor(rmax[r], off));
    float alpha[4], rsum[4];
    #pragma unroll
    for (int r = 0; r < 4; r++) {
      float mn = fmaxf(m_old[r], rmax[r]);
      alpha[r] = __expf(m_old[r] - mn);
      m_old[r] = mn;
      rsum[r] = 0.f;
    }
    #pragma unroll
    for (int nt = 0; nt < 4; nt++)
      #pragma unroll
      for (int r = 0; r < 4; r++) {
        float p = __expf(s[nt][r] - m_old[r]);
        rsum[r] += p;
        Ps[w][(quad * 4 + r) * 72 + nt * 16 + l15] = (f16)p;
      }
    #pragma unroll
    for (int off = 1; off < 16; off <<= 1)
      #pragma unroll
      for (int r = 0; r < 4; r++)
        rsum[r] += __shfl_xor(rsum[r], off);
    #pragma unroll
    for (int r = 0; r < 4; r++) l_old[r] = l_old[r] * alpha[r] + rsum[r];
    #pragma unroll
    for (int nt = 0; nt < 4; nt++)
      #pragma unroll
      for (int r = 0; r < 4; r++) o[nt][r] *= alpha[r];
    #pragma unroll
    for (int ks = 0; ks < 2; ks++) {
      f16x8 pa = *(const f16x8*)(&Ps[w][l15 * 72 + ks * 32 + quad * 8]);
      #pragma unroll
      for (int nt = 0; nt < 4; nt++) {
        f16x8 vf = *(const f16x8*)(Vs + (ks * 4 + nt) * 512 + lane * 8);
        o[nt] = __builtin_amdgcn_mfma_f32_16x16x32_f16(pa, vf, o[nt], 0, 0, 0);
      }
    }
    __syncthreads();
  }
  #pragma unroll
  for (int r = 0; r < 4; r++) {
    float inv = 1.f / l_old[r];
    int n = qt * 64 + w * 16 + quad * 4 + r;
    #pragma unroll
    for (int nt = 0; nt < 4; nt++)
      out[((size_t)(b_ * 1024 + n)) * 512 + h * 64 + nt * 16 + l15] = o[nt][r] * inv;
  }
}

// ----------------------------------------------------------------------- host
extern "C" void kernel_launch(void* const* d_in, const int* in_sizes, int n_in,
                              void* d_out, int out_size, void* d_ws, size_t ws_size,
                              hipStream_t stream) {
  const float* x  = (const float*)d_in[0];
  const float* Wq = (const float*)d_in[1];
  const float* bq = (const float*)d_in[2];
  const float* Wk = (const float*)d_in[3];
  const float* bk = (const float*)d_in[4];
  const float* Wv = (const float*)d_in[5];
  const float* bv = (const float*)d_in[6];
  const float* Wg = (const float*)d_in[7];
  const float* bg = (const float*)d_in[8];
  float* out = (float*)d_out;

  const size_t NX = (size_t)TOK * EDIM;        // 2M elems
  const size_t NWG = (size_t)GCOLS * EDIM;     // 16.8M elems
  const size_t NW = (size_t)EDIM * EDIM;       // 256K elems

  char* p = (char*)d_ws;
  u16* xf  = (u16*)p; p += NX * 2;             // x fp16
  u16* Wgt = (u16*)p; p += NWG * 2;            // Wg^T fp16 (33.5 MB)
  u16* Wqt = (u16*)p; p += NW * 2;
  u16* Wkt = (u16*)p; p += NW * 2;
  u16* Wvt = (u16*)p; p += NW * 2;
  u16* qh  = (u16*)p; p += NX * 2;             // q fp16 [B][H][N][D]
  u16* kf  = (u16*)p; p += NX * 2;             // k fp16
  u16* vT  = (u16*)p; p += NX * 2;             // v^T fp16
  float* qgp = (float*)p; p += NX * 4 * 2;     // qg fp32 partials [2][B][H][N][D]

  hipLaunchKernelGGL(cast_f16_k, dim3(NX / 1024), dim3(256), 0, stream,
                     x, xf, (int)NX);
  hipLaunchKernelGGL(transpose_f16_k, dim3(EDIM / 32, EDIM / 32), dim3(32, 8), 0, stream,
                     Wq, Wqt, EDIM, EDIM);
  hipLaunchKernelGGL(transpose_f16_k, dim3(EDIM / 32, EDIM / 32), dim3(32, 8), 0, stream,
                     Wk, Wkt, EDIM, EDIM);
  hipLaunchKernelGGL(transpose_f16_k, dim3(EDIM / 32, EDIM / 32), dim3(32, 8), 0, stream,
                     Wv, Wvt, EDIM, EDIM);
  hipLaunchKernelGGL(transpose_f16_k, dim3(GCOLS / 32, EDIM / 32), dim3(32, 8), 0, stream,
                     Wg, Wgt, EDIM, GCOLS);
  hipLaunchKernelGGL(qkv_gemm_k, dim3(TOK / 128, EDIM / 128, 3), dim3(256), 0, stream,
                     xf, Wqt, Wkt, Wvt, bq, bk, bv, qh, kf, vT);
  hipLaunchKernelGGL(qg_fused_k, dim3(512), dim3(512), 0, stream,
                     xf, Wgt, bg, qh, qgp);
  hipLaunchKernelGGL(attn_k, dim3(512), dim3(256), 0, stream,
                     qgp, kf, vT, out);
}